// Round 17
// baseline (78.021 us; speedup 1.0000x reference)
//
#include <hip/hip_runtime.h>

#define NB 64        // bins
#define HW 65536     // pixels per channel (256*256)
#define NCH 24       // B*C = 8*3
#define SPLIT 8      // segments per channel-image
#define NSLOT 76     // slots = bin + 6, bins -6..69
#define NCOL 128     // columns; thread pair (c, c+128) shares column c

typedef __attribute__((ext_vector_type(2))) float f32x2;

// w_b(x) = exp(-K*(f-b)^2), f = 63x, K = 2048/3969.
// Even-aligned 12-tap window (r14-verified, absmax 0.0): e0 = (ni-5)&~1,
// slots e0+6 .. e0+17, parity thread p handles taps k' ≡ p (mod 2): 6 taps
// at byte stride 1024 = 4 st64-b32 units -> offsets 0,4 / 8,12 / 16,20.
//
// r17: PING-PONG + SOFTWARE PIPELINE — the clean test of the cross-pixel
// RMW chain theory (the one mechanism consistent with ALL eight null levers
// r3..r16: consecutive pixels' windows overlap in one LDS object, so the
// pipe serializes W(e) commit -> R(e+1)). Two DISTINCT __shared__ arrays
// HA/HB alternate per pixel: R(e+1) targets the other array than W(e), so
// issuing R(e+1) BEFORE W(e) is semantically safe (disjoint), and lgkmcnt(6)
// leaves W(e-1)+R(e+1) in flight while the adds run — write-commit latency
// hidden. In-order DS completion keeps R(e+2)-after-W(e) correct (same
// array, issued later). Occupancy de-confounded vs r7: 256 threads,
// 77.8 KB LDS -> 2 blocks/CU, same as r9 (best).
// Banks: addr = slot*512 + col*4 (+array base); 512 == 0 mod 32 banks ->
// bank = col%32 uniform 2-way (free). No atomics (r13: ~200cy).
__global__ __launch_bounds__(256) void chml_hist(const float* __restrict__ pred,
                                                 const float* __restrict__ targ,
                                                 float* __restrict__ part,
                                                 float* __restrict__ out) {
  const int seg = blockIdx.x;   // 0..SPLIT-1
  const int ct  = blockIdx.y;   // 0..2*NCH-1
  const float* src = (ct < NCH) ? (pred + (size_t)ct * HW)
                                : (targ + (size_t)(ct - NCH) * HW);
  const int tid = threadIdx.x;
  const int c   = tid & (NCOL - 1);   // column
  const int p   = tid >> 7;           // parity (wave-uniform: waves 0-1 / 2-3)

  if (seg == 0 && ct == 0 && tid == 0) out[0] = 0.0f;  // for chan's atomicAdd

  // column c owns 64 consecutive pixels; 16 float4 issued up front
  // (both parity threads read the same data; L1/L2 absorbs — r14 precedent)
  const float4* s4 = (const float4*)(src + (size_t)seg * (HW / SPLIT));
  float4 P[16];
#pragma unroll
  for (int i = 0; i < 16; ++i) P[i] = s4[c * 16 + i];

  __shared__ float HA[NSLOT][NCOL];   // 38912 B
  __shared__ float HB[NSLOT][NCOL];   // 38912 B  (total 77824 -> 2 blocks/CU)
  {
    float4* za = (float4*)&HA[0][0];
    float4* zb = (float4*)&HB[0][0];
#pragma unroll
    for (int i = tid; i < NSLOT * NCOL / 4; i += 256) {
      za[i] = make_float4(0.f, 0.f, 0.f, 0.f);
      zb[i] = make_float4(0.f, 0.f, 0.f, 0.f);
    }
  }
  __syncthreads();

  const float K  = 0.51599899f;      // 2048/3969
  const float C1 = 5.96905619e-01f;  // exp(-K*1)
  const float C2 = 1.26927917e-01f;  // exp(-K*4)
  const float C3 = 9.61165782e-03f;  // exp(-K*9)
  const float C4 = 2.59240329e-04f;  // exp(-K*16)
  const float C5 = 2.49029640e-06f;  // exp(-K*25)
  const float C6 = 8.56260000e-09f;  // exp(-K*36)

  typedef __attribute__((address_space(3))) float lds_f32;
  const unsigned baseA =
      (unsigned)(size_t)((lds_f32*)&HA[0][0] + c) + ((unsigned)p << 9);
  const unsigned baseB =
      (unsigned)(size_t)((lds_f32*)&HB[0][0] + c) + ((unsigned)p << 9);

  // pixel values as statically-indexed scalars (all indices constant
  // after full unroll — rule #20 safe)
  float pv[64];
#pragma unroll
  for (int i = 0; i < 16; ++i) {
    pv[4*i+0] = P[i].x; pv[4*i+1] = P[i].y;
    pv[4*i+2] = P[i].z; pv[4*i+3] = P[i].w;
  }

  // ---- prologue: pixel 0 -> array A
  float f0 = pv[0] * 63.0f;
  int   ni0 = (int)rintf(f0);
  int   e00 = (ni0 - 5) & ~1;
  float dp_cur = f0 - (float)(e00 + 6);
  unsigned a_cur = baseA + ((unsigned)(e00 + 6) << 9);
  f32x2 t01 = {0.f,0.f}, t23 = {0.f,0.f}, t45 = {0.f,0.f};
  asm volatile("ds_read2st64_b32 %0, %1 offset0:0 offset1:4"
               : "=v"(t01) : "v"(a_cur));
  asm volatile("ds_read2st64_b32 %0, %1 offset0:8 offset1:12"
               : "=v"(t23) : "v"(a_cur));
  asm volatile("ds_read2st64_b32 %0, %1 offset0:16 offset1:20"
               : "=v"(t45) : "v"(a_cur));

#pragma unroll
  for (int g = 0; g < 64; ++g) {
    // ---- issue next pixel's reads into the OTHER array (before this
    //      pixel's writes — safe: distinct LDS objects)
    unsigned a_nxt = 0; float dp_nxt = 0.f;
    f32x2 u01 = {0.f,0.f}, u23 = {0.f,0.f}, u45 = {0.f,0.f};
    if (g < 63) {
      float fn  = pv[g + 1] * 63.0f;
      int   nin = (int)rintf(fn);
      int   e0n = (nin - 5) & ~1;
      dp_nxt = fn - (float)(e0n + 6);
      a_nxt  = (((g + 1) & 1) ? baseB : baseA) + ((unsigned)(e0n + 6) << 9);
      asm volatile("ds_read2st64_b32 %0, %1 offset0:0 offset1:4"
                   : "=v"(u01) : "v"(a_nxt));
      asm volatile("ds_read2st64_b32 %0, %1 offset0:8 offset1:12"
                   : "=v"(u23) : "v"(a_nxt));
      asm volatile("ds_read2st64_b32 %0, %1 offset0:16 offset1:20"
                   : "=v"(u45) : "v"(a_nxt));
    }
    // ---- weight ladder for current pixel (overlaps all DS latency)
    float dp = dp_cur;
    float w0 = __expf(dp * dp * -K);
    float mp = __expf(dp * (2.0f * K));
    float mn = __expf(dp * (-2.0f * K));
    float mp2 = mp * mp, mp3 = mp2 * mp, mp4 = mp2 * mp2;
    float mn2 = mn * mn, mn3 = mn2 * mn, mn4 = mn2 * mn2, mn5 = mn4 * mn,
          mn6 = mn3 * mn3, mp5 = mp4 * mp;
    float W0, W1, W2, W3, W4, W5;
    if (p == 0) {               // even taps: r = -6,-4,-2,0,2,4
      W0 = w0 * (C6 * mn6); W1 = w0 * (C4 * mn4); W2 = w0 * (C2 * mn2);
      W3 = w0;              W4 = w0 * (C2 * mp2); W5 = w0 * (C4 * mp4);
    } else {                    // odd taps: r = -5,-3,-1,1,3,5
      W0 = w0 * (C5 * mn5); W1 = w0 * (C3 * mn3); W2 = w0 * (C1 * mn);
      W3 = w0 * (C1 * mp);  W4 = w0 * (C3 * mp3); W5 = w0 * (C5 * mp5);
    }
    // ---- wait for t only: lgkmcnt(6) leaves W(g-1)(3) + u(3) in flight
    //      (g=0: no writes yet; g=63: no u -> lgkmcnt(3) in both cases)
    if (g == 0 || g == 63)
      asm volatile("s_waitcnt lgkmcnt(3)"
                   : "+v"(t01), "+v"(t23), "+v"(t45));
    else
      asm volatile("s_waitcnt lgkmcnt(6)"
                   : "+v"(t01), "+v"(t23), "+v"(t45));
    __builtin_amdgcn_sched_barrier(0);   // rule #18
    float d0 = t01.x + W0, d1 = t01.y + W1;
    float d2 = t23.x + W2, d3 = t23.y + W3;
    float d4 = t45.x + W4, d5 = t45.y + W5;
    // ---- writeback current pixel
    asm volatile("ds_write2st64_b32 %2, %0, %1 offset0:0 offset1:4"
                 :: "v"(d0), "v"(d1), "v"(a_cur) : "memory");
    asm volatile("ds_write2st64_b32 %2, %0, %1 offset0:8 offset1:12"
                 :: "v"(d2), "v"(d3), "v"(a_cur) : "memory");
    asm volatile("ds_write2st64_b32 %2, %0, %1 offset0:16 offset1:20"
                 :: "v"(d4), "v"(d5), "v"(a_cur) : "memory");
    // ---- rotate pipeline state
    t01 = u01; t23 = u23; t45 = u45; a_cur = a_nxt; dp_cur = dp_nxt;
  }
  __syncthreads();

  // Fold: thread s (<76) sums slot s over 128 cols in BOTH arrays,
  // b128 x staggered by s (r14-verified pattern).
  if (tid < NSLOT) {
    const int s = tid;
    float acc = 0.f;
#pragma unroll 4
    for (int i = 0; i < 32; ++i) {
      float4 va = *(const float4*)&HA[s][4 * ((i + s) & 31)];
      float4 vb = *(const float4*)&HB[s][4 * ((i + s) & 31)];
      acc += ((va.x + va.y) + (va.z + va.w)) + ((vb.x + vb.y) + (vb.z + vb.w));
    }
    int bin = s - 6;
    if (bin >= 0 && bin < NB)
      part[((size_t)ct * SPLIT + seg) * NB + bin] = acc;
  }
}

// Merged tail: per-channel CDF loss, pre-scaled atomicAdd into out.
// 24 blocks x 64 threads (parallel across CUs — r5 lesson). out was zeroed
// by hist block (0,0); stream order makes this race-free.
__global__ __launch_bounds__(64) void chml_chan(const float* __restrict__ part,
                                                float* __restrict__ out) {
  const int c    = blockIdx.x;
  const int lane = threadIdx.x;
  float vp = 0.0f, vt = 0.0f;
#pragma unroll
  for (int s = 0; s < SPLIT; ++s) {
    vp += part[((size_t)c * SPLIT + s) * NB + lane];
    vt += part[((size_t)(c + NCH) * SPLIT + s) * NB + lane];
  }
  // inclusive prefix scan across 64 lanes
#pragma unroll
  for (int off = 1; off < 64; off <<= 1) {
    float up = __shfl_up(vp, off, 64);
    float ut = __shfl_up(vt, off, 64);
    if (lane >= off) { vp += up; vt += ut; }
  }
  float totp = __shfl(vp, 63, 64);
  float tott = __shfl(vt, 63, 64);
  float l = fabsf(vp / (totp + 1e-7f) - vt / (tott + 1e-7f));
#pragma unroll
  for (int off = 32; off >= 1; off >>= 1) l += __shfl_xor(l, off, 64);
  if (lane == 0) atomicAdd(out, l * (1.0f / (float)(NCH * NB)));
}

extern "C" void kernel_launch(void* const* d_in, const int* in_sizes, int n_in,
                              void* d_out, int out_size, void* d_ws, size_t ws_size,
                              hipStream_t stream) {
  const float* pred = (const float*)d_in[0];
  const float* targ = (const float*)d_in[1];
  float* part = (float*)d_ws;        // 48*8*64 floats = 96 KB

  dim3 grid(SPLIT, 2 * NCH);
  chml_hist<<<grid, 256, 0, stream>>>(pred, targ, part, (float*)d_out);
  chml_chan<<<NCH, 64, 0, stream>>>(part, (float*)d_out);
}